// Round 15
// baseline (69.782 us; speedup 1.0000x reference)
//
#include <hip/hip_runtime.h>
#include <hip/hip_bf16.h>

// out[b,o] = sum_{i,n} T_n(x[b,i]) * w[o,i,n]
// GEMM view: M=B=65536, N=O=32, K=I*8=2048. MFMA v_mfma_f32_32x32x16_bf16.
// Round-13 (2nd resubmit; rounds 13/14 benches were infra failures): kill the
// wB L2 re-stream. Each wave loads its 32 B-fragments ONCE into registers
// (ball[32], statically indexed) and amortizes them over TWO row-tiles per
// block (grid 1024: tiles T0, T0+1024). Inner loop has ZERO vmem
// instructions. Tile-2's x loads are issued before tile-1's compute and fly
// underneath it (wave-private, no extra barriers). R10-proven staging
// swizzle, addressing, math, and epilogue throughout.

typedef __attribute__((ext_vector_type(8)))  short bf16x8;
typedef __attribute__((ext_vector_type(16))) float f32x16;
typedef __attribute__((ext_vector_type(4)))  float f32x4;

__device__ __forceinline__ short f2b(float f) {     // RN (prep only)
    __hip_bfloat16 h = __float2bfloat16(f);
    short s;
    __builtin_memcpy(&s, &h, sizeof(s));
    return s;
}

// pack {hi16(hi), hi16(lo)} in ONE v_perm_b32 (truncating bf16 pack)
__device__ __forceinline__ unsigned pkbf_tr(float lo, float hi) {
    unsigned a, b;
    __builtin_memcpy(&a, &hi, 4);
    __builtin_memcpy(&b, &lo, 4);
    return __builtin_amdgcn_perm(a, b, 0x07060302u);
}

// Pack w [32][256][8] fp32 -> wB[kc2][lane][jj] bf16 in B-fragment order:
//   o = lane&31, g = lane>>5, i = 2*kc2 + (jj>>2), n = 4*g + (jj&3)
// (HW-verified: rounds 2-12 passed with this layout)
__global__ __launch_bounds__(256) void prep_w_kernel(const float* __restrict__ w,
                                                     short* __restrict__ wB) {
    int idx = blockIdx.x * 256 + threadIdx.x;     // 0..65535
    int kc2 = idx >> 9;
    int l   = (idx >> 3) & 63;
    int jj  = idx & 7;
    int o = l & 31, g = l >> 5;
    int i = 2 * kc2 + (jj >> 2);
    int n = 4 * g + (jj & 3);
    wB[idx] = f2b(w[(o * 256 + i) * 8 + n]);
}

__global__ __launch_bounds__(256, 4) void cheb_mm_kernel(const float* __restrict__ x,
                                                         const short* __restrict__ wB,
                                                         float* __restrict__ out) {
    __shared__ float smem[8192];                  // 32 KB: x tile, then partials
    const int tid = threadIdx.x;
    const int wv  = tid >> 6;                     // K-quarter / column-slice
    const int l   = tid & 63;
    const int g   = l >> 5;                       // i-parity this lane computes
    const int r0  = l & 31;                       // batch row in tile / o column
    const int f4l = l & 15;                       // 16 float4 per row-slice
    const int rsub = l >> 4;                      // 4 rows per pass

    float4 stg[8];                                // in-flight x slice

    auto ISSUE = [&](long long rowB) {            // global -> regs (R8/R10)
        const float4* xg4 = (const float4*)(x + rowB * 256);
        #pragma unroll
        for (int q = 0; q < 8; ++q)
            stg[q] = xg4[(q * 4 + rsub) * 64 + wv * 16 + f4l];
    };
    auto WRITE = [&]() {                          // regs -> LDS, proven swizzle
        #pragma unroll
        for (int q = 0; q < 8; ++q) {
            const int row  = q * 4 + rsub;
            const int base = row * 256 + wv * 64;
            const int s    = row & 31;
            const int p0 = 2 * f4l, p1 = 2 * f4l + 1;
            *(float2*)&smem[base + 2 * (p0 ^ s)] = make_float2(stg[q].x, stg[q].y);
            *(float2*)&smem[base + 2 * (p1 ^ s)] = make_float2(stg[q].z, stg[q].w);
        }
    };

    const long long rowB0 = (long long)blockIdx.x * 32;
    const long long rowB1 = (long long)(blockIdx.x + 1024) * 32;

    ISSUE(rowB0);

    // B-fragments for this wave's K-quarter: loaded ONCE, live in registers.
    // Full unroll => static indices => VGPRs (R9: allocates at VGPR=128).
    const bf16x8* wq = (const bf16x8*)wB + wv * 2048 + l;
    bf16x8 ball[32];
    #pragma unroll
    for (int t = 0; t < 32; ++t) ball[t] = wq[t * 64];

    WRITE();                                      // tile-0 x lands
    ISSUE(rowB1);                                 // tile-1 x flies under compute

    const float* sf = smem;
    const int base0 = r0 * 256 + wv * 64 + g + (r0 << 1);   // R10 addressing

    #pragma unroll
    for (int tile = 0; tile < 2; ++tile) {
        const long long rowB = tile ? rowB1 : rowB0;

        // ---- compute from LDS: zero vmem in the loop (R10-proven body) ----
        f32x16 accA{}, accB{};
        float xc[4];
        #pragma unroll
        for (int j = 0; j < 4; ++j) xc[j] = sf[base0 ^ (j << 1)];

        #pragma unroll
        for (int t = 0; t < 32; ++t) {
            const bf16x8 bfrag = ball[t];
            const float  xv    = xc[t & 3];
            if (t + 4 < 32) xc[t & 3] = sf[base0 ^ ((t + 4) << 1)];

            const float x2 = xv + xv;
            const float T2 = fmaf(x2, xv, -1.f);
            const float T3 = fmaf(x2, T2, -xv);
            const float T4 = fmaf(x2, T3, -T2);
            const float T5 = fmaf(x2, T4, -T3);
            const float T6 = fmaf(x2, T5, -T4);
            const float T7 = fmaf(x2, T6, -T5);
            unsigned R0 = pkbf_tr(1.f, xv);       // 1 v_perm_b32 each
            unsigned R1 = pkbf_tr(T2, T3);
            unsigned R2 = pkbf_tr(T4, T5);
            unsigned R3 = pkbf_tr(T6, T7);
            auto r02 = __builtin_amdgcn_permlane32_swap(R0, R2, false, false);
            auto r13 = __builtin_amdgcn_permlane32_swap(R1, R3, false, false);
            union { unsigned u[4]; bf16x8 v; } af;
            af.u[0] = r02[0]; af.u[1] = r13[0];
            af.u[2] = r02[1]; af.u[3] = r13[1];
            if (t & 1)
                accB = __builtin_amdgcn_mfma_f32_32x32x16_bf16(af.v, bfrag, accB, 0, 0, 0);
            else
                accA = __builtin_amdgcn_mfma_f32_32x32x16_bf16(af.v, bfrag, accA, 0, 0, 0);
        }
        const f32x16 acc = accA + accB;

        // ---- partials into this wave's own (dead) slice, 1 barrier ----
        #pragma unroll
        for (int r = 0; r < 16; ++r) {
            const int rloc = (r & 3) + 8 * (r >> 2) + 4 * g;   // C/D row
            smem[rloc * 256 + wv * 64 + r0] = acc[r];
        }
        __syncthreads();

        // ---- cross-wave reduce + coalesced f32x4 store ----
        {
            float* op = out + rowB * 32;
            const int f   = tid * 4;
            const int row = f >> 5;
            const int c2  = f & 31;
            const int b   = row * 256 + c2;
            f32x4 v0 = *(const f32x4*)&smem[b];
            f32x4 v1 = *(const f32x4*)&smem[b + 64];
            f32x4 v2 = *(const f32x4*)&smem[b + 128];
            f32x4 v3 = *(const f32x4*)&smem[b + 192];
            f32x4 s = (v0 + v1) + (v2 + v3);
            *(f32x4*)(op + f) = s;
        }

        if (tile == 0) {
            __syncthreads();                      // all reduces done
            WRITE();                              // tile-1 x lands (was in flight)
        }
    }
}

extern "C" void kernel_launch(void* const* d_in, const int* in_sizes, int n_in,
                              void* d_out, int out_size, void* d_ws, size_t ws_size,
                              hipStream_t stream) {
    const float* x = (const float*)d_in[0];   // [65536, 256] fp32
    const float* w = (const float*)d_in[1];   // [32, 256, 8] fp32
    float* out = (float*)d_out;               // [65536, 32] fp32
    short* wB = (short*)d_ws;                 // 128 KB bf16 packed weights

    prep_w_kernel<<<256, 256, 0, stream>>>(w, wB);
    cheb_mm_kernel<<<1024, 256, 0, stream>>>(x, wB, out);
}

// Round 16
// 30.212 us; speedup vs baseline: 2.3098x; 2.3098x over previous
//
#include <hip/hip_runtime.h>
#include <hip/hip_bf16.h>

// out[b,o] = sum_{i,n} T_n(x[b,i]) * w[o,i,n]
// GEMM view: M=B=65536, N=O=32, K=I*8=2048. MFMA v_mfma_f32_32x32x16_bf16.
// Round-16 = Round-13 executed correctly: B-fragments in registers without
// spill. launch_bounds(256,2) raises the VGPR cap to 256 (R13's (256,4)
// capped at 128 -> ball[32] spilled to scratch: VGPR=64, FETCH 97MB, 70us).
// Single accumulator (saves 16 VGPR; ~34 VALU cyc between MFMAs >> MFMA
// latency). Grid 1024 x 2 row-tiles: wB L2 traffic halved, tile-1 x loads
// fly under tile-0 compute. Inner loop has ZERO vmem instructions.
// R10-proven staging swizzle, addressing, math, epilogue.

typedef __attribute__((ext_vector_type(8)))  short bf16x8;
typedef __attribute__((ext_vector_type(16))) float f32x16;
typedef __attribute__((ext_vector_type(4)))  float f32x4;

__device__ __forceinline__ short f2b(float f) {     // RN (prep only)
    __hip_bfloat16 h = __float2bfloat16(f);
    short s;
    __builtin_memcpy(&s, &h, sizeof(s));
    return s;
}

// pack {hi16(hi), hi16(lo)} in ONE v_perm_b32 (truncating bf16 pack)
__device__ __forceinline__ unsigned pkbf_tr(float lo, float hi) {
    unsigned a, b;
    __builtin_memcpy(&a, &hi, 4);
    __builtin_memcpy(&b, &lo, 4);
    return __builtin_amdgcn_perm(a, b, 0x07060302u);
}

// Pack w [32][256][8] fp32 -> wB[kc2][lane][jj] bf16 in B-fragment order:
//   o = lane&31, g = lane>>5, i = 2*kc2 + (jj>>2), n = 4*g + (jj&3)
// (HW-verified: rounds 2-15 passed with this layout)
__global__ __launch_bounds__(256) void prep_w_kernel(const float* __restrict__ w,
                                                     short* __restrict__ wB) {
    int idx = blockIdx.x * 256 + threadIdx.x;     // 0..65535
    int kc2 = idx >> 9;
    int l   = (idx >> 3) & 63;
    int jj  = idx & 7;
    int o = l & 31, g = l >> 5;
    int i = 2 * kc2 + (jj >> 2);
    int n = 4 * g + (jj & 3);
    wB[idx] = f2b(w[(o * 256 + i) * 8 + n]);
}

__global__ __launch_bounds__(256, 2) void cheb_mm_kernel(const float* __restrict__ x,
                                                         const short* __restrict__ wB,
                                                         float* __restrict__ out) {
    __shared__ float smem[8192];                  // 32 KB: x tile, then partials
    const int tid = threadIdx.x;
    const int wv  = tid >> 6;                     // K-quarter / column-slice
    const int l   = tid & 63;
    const int g   = l >> 5;                       // i-parity this lane computes
    const int r0  = l & 31;                       // batch row in tile / o column
    const int f4l = l & 15;                       // 16 float4 per row-slice
    const int rsub = l >> 4;                      // 4 rows per pass

    float4 stg[8];                                // in-flight x slice

    auto ISSUE = [&](long long rowB) {            // global -> regs (R8/R10)
        const float4* xg4 = (const float4*)(x + rowB * 256);
        #pragma unroll
        for (int q = 0; q < 8; ++q)
            stg[q] = xg4[(q * 4 + rsub) * 64 + wv * 16 + f4l];
    };
    auto WRITE = [&]() {                          // regs -> LDS, proven swizzle
        #pragma unroll
        for (int q = 0; q < 8; ++q) {
            const int row  = q * 4 + rsub;
            const int base = row * 256 + wv * 64;
            const int s    = row & 31;
            const int p0 = 2 * f4l, p1 = 2 * f4l + 1;
            *(float2*)&smem[base + 2 * (p0 ^ s)] = make_float2(stg[q].x, stg[q].y);
            *(float2*)&smem[base + 2 * (p1 ^ s)] = make_float2(stg[q].z, stg[q].w);
        }
    };

    const long long rowB0 = (long long)blockIdx.x * 32;
    const long long rowB1 = (long long)(blockIdx.x + 1024) * 32;

    ISSUE(rowB0);

    // B-fragments for this wave's K-quarter: loaded ONCE, live in registers.
    // Full unroll => static indices => VGPRs. (256,2) cap = 256 regs: fits.
    const bf16x8* wq = (const bf16x8*)wB + wv * 2048 + l;
    bf16x8 ball[32];
    #pragma unroll
    for (int t = 0; t < 32; ++t) ball[t] = wq[t * 64];

    WRITE();                                      // tile-0 x lands
    ISSUE(rowB1);                                 // tile-1 x flies under compute

    const float* sf = smem;
    const int base0 = r0 * 256 + wv * 64 + g + (r0 << 1);   // R10 addressing

    #pragma unroll
    for (int tile = 0; tile < 2; ++tile) {
        const long long rowB = tile ? rowB1 : rowB0;

        // ---- compute from LDS: zero vmem in the loop (R10-proven body) ----
        f32x16 acc{};
        float xc[4];
        #pragma unroll
        for (int j = 0; j < 4; ++j) xc[j] = sf[base0 ^ (j << 1)];

        #pragma unroll
        for (int t = 0; t < 32; ++t) {
            const bf16x8 bfrag = ball[t];
            const float  xv    = xc[t & 3];
            if (t + 4 < 32) xc[t & 3] = sf[base0 ^ ((t + 4) << 1)];

            const float x2 = xv + xv;
            const float T2 = fmaf(x2, xv, -1.f);
            const float T3 = fmaf(x2, T2, -xv);
            const float T4 = fmaf(x2, T3, -T2);
            const float T5 = fmaf(x2, T4, -T3);
            const float T6 = fmaf(x2, T5, -T4);
            const float T7 = fmaf(x2, T6, -T5);
            unsigned R0 = pkbf_tr(1.f, xv);       // 1 v_perm_b32 each
            unsigned R1 = pkbf_tr(T2, T3);
            unsigned R2 = pkbf_tr(T4, T5);
            unsigned R3 = pkbf_tr(T6, T7);
            auto r02 = __builtin_amdgcn_permlane32_swap(R0, R2, false, false);
            auto r13 = __builtin_amdgcn_permlane32_swap(R1, R3, false, false);
            union { unsigned u[4]; bf16x8 v; } af;
            af.u[0] = r02[0]; af.u[1] = r13[0];
            af.u[2] = r02[1]; af.u[3] = r13[1];
            acc = __builtin_amdgcn_mfma_f32_32x32x16_bf16(af.v, bfrag, acc, 0, 0, 0);
        }

        // ---- partials into this wave's own (dead) slice, 1 barrier ----
        #pragma unroll
        for (int r = 0; r < 16; ++r) {
            const int rloc = (r & 3) + 8 * (r >> 2) + 4 * g;   // C/D row
            smem[rloc * 256 + wv * 64 + r0] = acc[r];
        }
        __syncthreads();

        // ---- cross-wave reduce + coalesced f32x4 store ----
        {
            float* op = out + rowB * 32;
            const int f   = tid * 4;
            const int row = f >> 5;
            const int c2  = f & 31;
            const int b   = row * 256 + c2;
            f32x4 v0 = *(const f32x4*)&smem[b];
            f32x4 v1 = *(const f32x4*)&smem[b + 64];
            f32x4 v2 = *(const f32x4*)&smem[b + 128];
            f32x4 v3 = *(const f32x4*)&smem[b + 192];
            f32x4 s = (v0 + v1) + (v2 + v3);
            *(f32x4*)(op + f) = s;
        }

        if (tile == 0) {
            __syncthreads();                      // all reduces done
            WRITE();                              // tile-1 x lands (was in flight)
        }
    }
}

extern "C" void kernel_launch(void* const* d_in, const int* in_sizes, int n_in,
                              void* d_out, int out_size, void* d_ws, size_t ws_size,
                              hipStream_t stream) {
    const float* x = (const float*)d_in[0];   // [65536, 256] fp32
    const float* w = (const float*)d_in[1];   // [32, 256, 8] fp32
    float* out = (float*)d_out;               // [65536, 32] fp32
    short* wB = (short*)d_ws;                 // 128 KB bf16 packed weights

    prep_w_kernel<<<256, 256, 0, stream>>>(w, wB);
    cheb_mm_kernel<<<1024, 256, 0, stream>>>(x, wB, out);
}

// Round 17
// 28.952 us; speedup vs baseline: 2.4103x; 1.0435x over previous
//
#include <hip/hip_runtime.h>
#include <hip/hip_bf16.h>

// out[b,o] = sum_{i,n} T_n(x[b,i]) * w[o,i,n]
// GEMM view: M=B=65536, N=O=32, K=I*8=2048. MFMA v_mfma_f32_32x32x16_bf16.
// Round-17 = Round-10 frame (2048 blocks, wave-private stage, 32KB LDS) with
// the B-latency stall removed:
//  - bfc depth 8 (covers ~320cy >= L2 latency; depth-4 covered only ~160)
//  - dual accumulator (break MFMA acc chain)
//  - af built as [r02[0],r02[1],r13[0],r13[1]] (two natural consecutive
//    pairs -> no per-iter v_movs); B pair-order in prep permuted identically
//    (jj in {2..5} -> jj^6), same k-bijection both operands => same result
//  - launch_bounds(256,4): VGPR ~120, 4 blocks/CU = 16 waves/CU

typedef __attribute__((ext_vector_type(8)))  short bf16x8;
typedef __attribute__((ext_vector_type(16))) float f32x16;
typedef __attribute__((ext_vector_type(4)))  float f32x4;

__device__ __forceinline__ short f2b(float f) {     // RN (prep only)
    __hip_bfloat16 h = __float2bfloat16(f);
    short s;
    __builtin_memcpy(&s, &h, sizeof(s));
    return s;
}

// pack {hi16(hi), hi16(lo)} in ONE v_perm_b32 (truncating bf16 pack)
__device__ __forceinline__ unsigned pkbf_tr(float lo, float hi) {
    unsigned a, b;
    __builtin_memcpy(&a, &hi, 4);
    __builtin_memcpy(&b, &lo, 4);
    return __builtin_amdgcn_perm(a, b, 0x07060302u);
}

// Pack w [32][256][8] fp32 -> wB[kc2][lane][jj] bf16 in B-fragment order,
// with u32-pair order permuted to match the new A-side af word order:
//   jjp = (2<=jj<6) ? jj^6 : jj;  o = lane&31, g = lane>>5,
//   i = 2*kc2 + (jjp>>2), n = 4*g + (jjp&3)
// (base layout HW-verified rounds 2-16; pair-swap is the same permutation
//  applied to the A-side af assembly => contraction identical)
__global__ __launch_bounds__(256) void prep_w_kernel(const float* __restrict__ w,
                                                     short* __restrict__ wB) {
    int idx = blockIdx.x * 256 + threadIdx.x;     // 0..65535
    int kc2 = idx >> 9;
    int l   = (idx >> 3) & 63;
    int jj  = idx & 7;
    int jjp = (jj >= 2 && jj < 6) ? (jj ^ 6) : jj;
    int o = l & 31, g = l >> 5;
    int i = 2 * kc2 + (jjp >> 2);
    int n = 4 * g + (jjp & 3);
    wB[idx] = f2b(w[(o * 256 + i) * 8 + n]);
}

__global__ __launch_bounds__(256, 4) void cheb_mm_kernel(const float* __restrict__ x,
                                                         const short* __restrict__ wB,
                                                         float* __restrict__ out) {
    __shared__ float smem[8192];                  // 32 KB: x tile, then partials
    const int tid = threadIdx.x;
    const int wv  = tid >> 6;                     // K-quarter / column-slice
    const int l   = tid & 63;
    const int g   = l >> 5;                       // i-parity this lane computes
    const int r0  = l & 31;                       // batch row in tile / o column
    const long long rowB = (long long)blockIdx.x * 32;

    const bf16x8* wq = (const bf16x8*)wB + wv * 2048 + l;
    // early B prefetch, depth 8: issue before staging, refill 8 ahead
    bf16x8 bfc[8];
    #pragma unroll
    for (int p = 0; p < 8; ++p) bfc[p] = wq[p * 64];

    // ---- wave-private stage: rows 0..31, float cols [wv*64, wv*64+64) ----
    // NO barrier: this wave is the only reader of this slice. (R8/R10-proven)
    {
        const float4* xg4 = (const float4*)(x + rowB * 256);
        const int f4l = l & 15;                   // 16 float4 per row-slice
        const int rsub = l >> 4;                  // 4 rows per pass
        float4 stg[8];
        #pragma unroll
        for (int q = 0; q < 8; ++q)
            stg[q] = xg4[(q * 4 + rsub) * 64 + wv * 16 + f4l];   // all in flight
        #pragma unroll
        for (int q = 0; q < 8; ++q) {
            const int row  = q * 4 + rsub;
            const int base = row * 256 + wv * 64; // dword base of slice row
            const int s    = row & 31;
            const int p0 = 2 * f4l, p1 = 2 * f4l + 1;   // local f2 idx 0..31
            *(float2*)&smem[base + 2 * (p0 ^ s)] = make_float2(stg[q].x, stg[q].y);
            *(float2*)&smem[base + 2 * (p1 ^ s)] = make_float2(stg[q].z, stg[q].w);
        }
    }

    // ---- compute: kc2 = wv*32+t, t=0..31 ----
    f32x16 accA{}, accB{};
    const float* sf = smem;
    const int base0 = r0 * 256 + wv * 64 + g + (r0 << 1);   // R10 addressing

    float xc[4];
    #pragma unroll
    for (int j = 0; j < 4; ++j) xc[j] = sf[base0 ^ (j << 1)];

    #pragma unroll
    for (int t = 0; t < 32; ++t) {
        const bf16x8 bfrag = bfc[t & 7];
        const float  xv    = xc[t & 3];
        if (t + 8 < 32) bfc[t & 7] = wq[(t + 8) * 64];
        if (t + 4 < 32) xc[t & 3]  = sf[base0 ^ ((t + 4) << 1)];

        const float x2 = xv + xv;
        const float T2 = fmaf(x2, xv, -1.f);
        const float T3 = fmaf(x2, T2, -xv);
        const float T4 = fmaf(x2, T3, -T2);
        const float T5 = fmaf(x2, T4, -T3);
        const float T6 = fmaf(x2, T5, -T4);
        const float T7 = fmaf(x2, T6, -T5);
        unsigned R0 = pkbf_tr(1.f, xv);           // 1 v_perm_b32 each
        unsigned R1 = pkbf_tr(T2, T3);
        unsigned R2 = pkbf_tr(T4, T5);
        unsigned R3 = pkbf_tr(T6, T7);
        // hazard-safe builtin; wiring verified rounds 6-16
        auto r02 = __builtin_amdgcn_permlane32_swap(R0, R2, false, false);
        auto r13 = __builtin_amdgcn_permlane32_swap(R1, R3, false, false);
        union { unsigned u[4]; bf16x8 v; } af;
        af.u[0] = r02[0]; af.u[1] = r02[1];       // natural consecutive pairs
        af.u[2] = r13[0]; af.u[3] = r13[1];       // (B pair-order matches)
        if (t & 1)
            accB = __builtin_amdgcn_mfma_f32_32x32x16_bf16(af.v, bfrag, accB, 0, 0, 0);
        else
            accA = __builtin_amdgcn_mfma_f32_32x32x16_bf16(af.v, bfrag, accA, 0, 0, 0);
    }
    const f32x16 acc = accA + accB;

    // ---- partials into this wave's own (dead) slice: no barrier needed ----
    #pragma unroll
    for (int r = 0; r < 16; ++r) {
        const int rloc = (r & 3) + 8 * (r >> 2) + 4 * g;   // C/D row (HW-verified)
        smem[rloc * 256 + wv * 64 + r0] = acc[r];
    }
    __syncthreads();                              // the block's ONLY barrier

    // ---- cross-wave reduce + coalesced f32x4 store of out[32][32] ----
    {
        float* op = out + rowB * 32;
        const int f   = tid * 4;                  // 1024 floats / 256 thr
        const int row = f >> 5;
        const int c2  = f & 31;
        const int b   = row * 256 + c2;
        f32x4 v0 = *(const f32x4*)&smem[b];
        f32x4 v1 = *(const f32x4*)&smem[b + 64];
        f32x4 v2 = *(const f32x4*)&smem[b + 128];
        f32x4 v3 = *(const f32x4*)&smem[b + 192];
        f32x4 s = (v0 + v1) + (v2 + v3);
        *(f32x4*)(op + f) = s;
    }
}

extern "C" void kernel_launch(void* const* d_in, const int* in_sizes, int n_in,
                              void* d_out, int out_size, void* d_ws, size_t ws_size,
                              hipStream_t stream) {
    const float* x = (const float*)d_in[0];   // [65536, 256] fp32
    const float* w = (const float*)d_in[1];   // [32, 256, 8] fp32
    float* out = (float*)d_out;               // [65536, 32] fp32
    short* wB = (short*)d_ws;                 // 128 KB bf16 packed weights

    prep_w_kernel<<<256, 256, 0, stream>>>(w, wB);
    cheb_mm_kernel<<<2048, 256, 0, stream>>>(x, wB, out);
}

// Round 18
// 28.768 us; speedup vs baseline: 2.4257x; 1.0064x over previous
//
#include <hip/hip_runtime.h>
#include <hip/hip_bf16.h>

// out[b,o] = sum_{i,n} T_n(x[b,i]) * w[o,i,n]
// GEMM view: M=B=65536, N=O=32, K=I*8=2048. MFMA v_mfma_f32_32x32x16_bf16.
// Round-18 = Round-17 (best, 28.95 us) with ONE lever: launch_bounds(256,3)
// -> 170-VGPR cap (was 128). Theory: compute runs at dependency LATENCY, not
// issue rate, because 128 regs leave no headroom to interleave consecutive
// iterations' Chebyshev chains (6 dependent fmas x 4cy). 12 waves/CU remain
// for TLP. xc depth widened 4->8 with the freed registers.

typedef __attribute__((ext_vector_type(8)))  short bf16x8;
typedef __attribute__((ext_vector_type(16))) float f32x16;
typedef __attribute__((ext_vector_type(4)))  float f32x4;

__device__ __forceinline__ short f2b(float f) {     // RN (prep only)
    __hip_bfloat16 h = __float2bfloat16(f);
    short s;
    __builtin_memcpy(&s, &h, sizeof(s));
    return s;
}

// pack {hi16(hi), hi16(lo)} in ONE v_perm_b32 (truncating bf16 pack)
__device__ __forceinline__ unsigned pkbf_tr(float lo, float hi) {
    unsigned a, b;
    __builtin_memcpy(&a, &hi, 4);
    __builtin_memcpy(&b, &lo, 4);
    return __builtin_amdgcn_perm(a, b, 0x07060302u);
}

// Pack w [32][256][8] fp32 -> wB[kc2][lane][jj] bf16 in B-fragment order,
// pair-permuted to match the A-side af word order (R17-proven):
//   jjp = (2<=jj<6) ? jj^6 : jj;  o = lane&31, g = lane>>5,
//   i = 2*kc2 + (jjp>>2), n = 4*g + (jjp&3)
__global__ __launch_bounds__(256) void prep_w_kernel(const float* __restrict__ w,
                                                     short* __restrict__ wB) {
    int idx = blockIdx.x * 256 + threadIdx.x;     // 0..65535
    int kc2 = idx >> 9;
    int l   = (idx >> 3) & 63;
    int jj  = idx & 7;
    int jjp = (jj >= 2 && jj < 6) ? (jj ^ 6) : jj;
    int o = l & 31, g = l >> 5;
    int i = 2 * kc2 + (jjp >> 2);
    int n = 4 * g + (jjp & 3);
    wB[idx] = f2b(w[(o * 256 + i) * 8 + n]);
}

__global__ __launch_bounds__(256, 3) void cheb_mm_kernel(const float* __restrict__ x,
                                                         const short* __restrict__ wB,
                                                         float* __restrict__ out) {
    __shared__ float smem[8192];                  // 32 KB: x tile, then partials
    const int tid = threadIdx.x;
    const int wv  = tid >> 6;                     // K-quarter / column-slice
    const int l   = tid & 63;
    const int g   = l >> 5;                       // i-parity this lane computes
    const int r0  = l & 31;                       // batch row in tile / o column
    const long long rowB = (long long)blockIdx.x * 32;

    const bf16x8* wq = (const bf16x8*)wB + wv * 2048 + l;
    // early B prefetch, depth 8: issue before staging, refill 8 ahead
    bf16x8 bfc[8];
    #pragma unroll
    for (int p = 0; p < 8; ++p) bfc[p] = wq[p * 64];

    // ---- wave-private stage: rows 0..31, float cols [wv*64, wv*64+64) ----
    // NO barrier: this wave is the only reader of this slice. (R8/R10-proven)
    {
        const float4* xg4 = (const float4*)(x + rowB * 256);
        const int f4l = l & 15;                   // 16 float4 per row-slice
        const int rsub = l >> 4;                  // 4 rows per pass
        float4 stg[8];
        #pragma unroll
        for (int q = 0; q < 8; ++q)
            stg[q] = xg4[(q * 4 + rsub) * 64 + wv * 16 + f4l];   // all in flight
        #pragma unroll
        for (int q = 0; q < 8; ++q) {
            const int row  = q * 4 + rsub;
            const int base = row * 256 + wv * 64; // dword base of slice row
            const int s    = row & 31;
            const int p0 = 2 * f4l, p1 = 2 * f4l + 1;   // local f2 idx 0..31
            *(float2*)&smem[base + 2 * (p0 ^ s)] = make_float2(stg[q].x, stg[q].y);
            *(float2*)&smem[base + 2 * (p1 ^ s)] = make_float2(stg[q].z, stg[q].w);
        }
    }

    // ---- compute: kc2 = wv*32+t, t=0..31 ----
    f32x16 accA{}, accB{};
    const float* sf = smem;
    const int base0 = r0 * 256 + wv * 64 + g + (r0 << 1);   // R10 addressing

    float xc[8];
    #pragma unroll
    for (int j = 0; j < 8; ++j) xc[j] = sf[base0 ^ (j << 1)];

    #pragma unroll
    for (int t = 0; t < 32; ++t) {
        const bf16x8 bfrag = bfc[t & 7];
        const float  xv    = xc[t & 7];
        if (t + 8 < 32) {
            bfc[t & 7] = wq[(t + 8) * 64];
            xc[t & 7]  = sf[base0 ^ ((t + 8) << 1)];
        }

        const float x2 = xv + xv;
        const float T2 = fmaf(x2, xv, -1.f);
        const float T3 = fmaf(x2, T2, -xv);
        const float T4 = fmaf(x2, T3, -T2);
        const float T5 = fmaf(x2, T4, -T3);
        const float T6 = fmaf(x2, T5, -T4);
        const float T7 = fmaf(x2, T6, -T5);
        unsigned R0 = pkbf_tr(1.f, xv);           // 1 v_perm_b32 each
        unsigned R1 = pkbf_tr(T2, T3);
        unsigned R2 = pkbf_tr(T4, T5);
        unsigned R3 = pkbf_tr(T6, T7);
        // hazard-safe builtin; wiring verified rounds 6-17
        auto r02 = __builtin_amdgcn_permlane32_swap(R0, R2, false, false);
        auto r13 = __builtin_amdgcn_permlane32_swap(R1, R3, false, false);
        union { unsigned u[4]; bf16x8 v; } af;
        af.u[0] = r02[0]; af.u[1] = r02[1];       // natural consecutive pairs
        af.u[2] = r13[0]; af.u[3] = r13[1];       // (B pair-order matches)
        if (t & 1)
            accB = __builtin_amdgcn_mfma_f32_32x32x16_bf16(af.v, bfrag, accB, 0, 0, 0);
        else
            accA = __builtin_amdgcn_mfma_f32_32x32x16_bf16(af.v, bfrag, accA, 0, 0, 0);
    }
    const f32x16 acc = accA + accB;

    // ---- partials into this wave's own (dead) slice: no barrier needed ----
    #pragma unroll
    for (int r = 0; r < 16; ++r) {
        const int rloc = (r & 3) + 8 * (r >> 2) + 4 * g;   // C/D row (HW-verified)
        smem[rloc * 256 + wv * 64 + r0] = acc[r];
    }
    __syncthreads();                              // the block's ONLY barrier

    // ---- cross-wave reduce + coalesced f32x4 store of out[32][32] ----
    {
        float* op = out + rowB * 32;
        const int f   = tid * 4;                  // 1024 floats / 256 thr
        const int row = f >> 5;
        const int c2  = f & 31;
        const int b   = row * 256 + c2;
        f32x4 v0 = *(const f32x4*)&smem[b];
        f32x4 v1 = *(const f32x4*)&smem[b + 64];
        f32x4 v2 = *(const f32x4*)&smem[b + 128];
        f32x4 v3 = *(const f32x4*)&smem[b + 192];
        f32x4 s = (v0 + v1) + (v2 + v3);
        *(f32x4*)(op + f) = s;
    }
}

extern "C" void kernel_launch(void* const* d_in, const int* in_sizes, int n_in,
                              void* d_out, int out_size, void* d_ws, size_t ws_size,
                              hipStream_t stream) {
    const float* x = (const float*)d_in[0];   // [65536, 256] fp32
    const float* w = (const float*)d_in[1];   // [32, 256, 8] fp32
    float* out = (float*)d_out;               // [65536, 32] fp32
    short* wB = (short*)d_ws;                 // 128 KB bf16 packed weights

    prep_w_kernel<<<256, 256, 0, stream>>>(w, wB);
    cheb_mm_kernel<<<2048, 256, 0, stream>>>(x, wB, out);
}

// Round 19
// 28.543 us; speedup vs baseline: 2.4448x; 1.0079x over previous
//
#include <hip/hip_runtime.h>
#include <hip/hip_bf16.h>

// out[b,o] = sum_{i,n} T_n(x[b,i]) * w[o,i,n]
// GEMM view: M=B=65536, N=O=32, K=I*8=2048. MFMA v_mfma_f32_32x32x16_bf16.
// Round-19: T3/T4-minimum 2-phase staging with REAL latency cover.
//  - wave-private 8KB slice staged as TWO 4KB K-chunks; BOTH chunks' global
//    loads issue in the prologue; chunk-1's ds_writes land at the 16-iter
//    boundary (compiler emits a COUNTED vmcnt for exactly those 4 loads:
//    B-refills issued later are not drained) -> 16-iter cover ~>= HBM latency
//  - K-major LDS slice [kf][row]: compute read = 1 ds_read_b32 with folded
//    offset (zero addr VALU, banks=r0, 2-way only = free); no XOR swizzle
//  - R17-proven math body, af natural-pair order + pair-permuted prep_w

typedef __attribute__((ext_vector_type(8)))  short bf16x8;
typedef __attribute__((ext_vector_type(16))) float f32x16;
typedef __attribute__((ext_vector_type(4)))  float f32x4;

__device__ __forceinline__ short f2b(float f) {     // RN (prep only)
    __hip_bfloat16 h = __float2bfloat16(f);
    short s;
    __builtin_memcpy(&s, &h, sizeof(s));
    return s;
}

// pack {hi16(hi), hi16(lo)} in ONE v_perm_b32 (truncating bf16 pack)
__device__ __forceinline__ unsigned pkbf_tr(float lo, float hi) {
    unsigned a, b;
    __builtin_memcpy(&a, &hi, 4);
    __builtin_memcpy(&b, &lo, 4);
    return __builtin_amdgcn_perm(a, b, 0x07060302u);
}

// Pack w [32][256][8] fp32 -> wB[kc2][lane][jj] bf16, pair-permuted to match
// the A-side af word order (R17/R18-proven):
//   jjp = (2<=jj<6) ? jj^6 : jj;  o = lane&31, g = lane>>5,
//   i = 2*kc2 + (jjp>>2), n = 4*g + (jjp&3)
__global__ __launch_bounds__(256) void prep_w_kernel(const float* __restrict__ w,
                                                     short* __restrict__ wB) {
    int idx = blockIdx.x * 256 + threadIdx.x;     // 0..65535
    int kc2 = idx >> 9;
    int l   = (idx >> 3) & 63;
    int jj  = idx & 7;
    int jjp = (jj >= 2 && jj < 6) ? (jj ^ 6) : jj;
    int o = l & 31, g = l >> 5;
    int i = 2 * kc2 + (jjp >> 2);
    int n = 4 * g + (jjp & 3);
    wB[idx] = f2b(w[(o * 256 + i) * 8 + n]);
}

__global__ __launch_bounds__(256, 3) void cheb_mm_kernel(const float* __restrict__ x,
                                                         const short* __restrict__ wB,
                                                         float* __restrict__ out) {
    __shared__ float smem[8192];                  // 32 KB: 4 x 8KB wave slices
    const int tid = threadIdx.x;
    const int wv  = tid >> 6;                     // K-quarter selector
    const int l   = tid & 63;
    const int g   = l >> 5;                       // i-parity this lane computes
    const int r0  = l & 31;                       // batch row / o column
    const int wvS = wv * 2048;                    // slice base (floats)
    const long long rowB = (long long)blockIdx.x * 32;

    const float4* xg4 = (const float4*)(x + rowB * 256);
    const bf16x8* wq  = (const bf16x8*)wB + wv * 2048 + l;

    // lane's stage coords: 8 lanes cover one row's 8 f4 of a chunk (128B run)
    const int srow8 = l >> 3;                     // row stride-8 group 0..7
    const int sf4   = l & 7;                      // f4 slot within chunk

    // ---- prologue: issue BOTH chunks' loads + B init; all in flight ----
    float4 s0[4], s1[4];
    #pragma unroll
    for (int q = 0; q < 4; ++q)                   // chunk0: kf [0,32)
        s0[q] = xg4[(q * 8 + srow8) * 64 + wv * 16 + sf4];
    #pragma unroll
    for (int q = 0; q < 4; ++q)                   // chunk1: kf [32,64)
        s1[q] = xg4[(q * 8 + srow8) * 64 + wv * 16 + 8 + sf4];
    bf16x8 bfc[8];
    #pragma unroll
    for (int p = 0; p < 8; ++p) bfc[p] = wq[p * 64];

    // ---- land chunk0 (auto counted vmcnt: only s0's 4 loads waited) ----
    #pragma unroll
    for (int q = 0; q < 4; ++q) {
        const int row = q * 8 + srow8;
        const int kf0 = 4 * sf4;                  // chunk0 kf base for lane
        smem[wvS + (kf0 + 0) * 32 + row] = s0[q].x;
        smem[wvS + (kf0 + 1) * 32 + row] = s0[q].y;
        smem[wvS + (kf0 + 2) * 32 + row] = s0[q].z;
        smem[wvS + (kf0 + 3) * 32 + row] = s0[q].w;
    }

    f32x16 accA{}, accB{};
    const float* sf = smem;
    const int base0 = wvS + g * 32 + r0;          // + t*64 per iter (folded)

    // ================= chunk 0: t = 0..15 =================
    {
        float xc[4];
        #pragma unroll
        for (int j = 0; j < 4; ++j) xc[j] = sf[base0 + j * 64];
        #pragma unroll
        for (int t = 0; t < 16; ++t) {
            const bf16x8 bfrag = bfc[t & 7];
            const float  xv    = xc[t & 3];
            bfc[t & 7] = wq[(t + 8) * 64];        // refill (t+8 <= 23 < 32)
            if (t + 4 < 16) xc[t & 3] = sf[base0 + (t + 4) * 64];

            const float x2 = xv + xv;
            const float T2 = fmaf(x2, xv, -1.f);
            const float T3 = fmaf(x2, T2, -xv);
            const float T4 = fmaf(x2, T3, -T2);
            const float T5 = fmaf(x2, T4, -T3);
            const float T6 = fmaf(x2, T5, -T4);
            const float T7 = fmaf(x2, T6, -T5);
            unsigned R0 = pkbf_tr(1.f, xv);
            unsigned R1 = pkbf_tr(T2, T3);
            unsigned R2 = pkbf_tr(T4, T5);
            unsigned R3 = pkbf_tr(T6, T7);
            auto r02 = __builtin_amdgcn_permlane32_swap(R0, R2, false, false);
            auto r13 = __builtin_amdgcn_permlane32_swap(R1, R3, false, false);
            union { unsigned u[4]; bf16x8 v; } af;
            af.u[0] = r02[0]; af.u[1] = r02[1];
            af.u[2] = r13[0]; af.u[3] = r13[1];
            if (t & 1)
                accB = __builtin_amdgcn_mfma_f32_32x32x16_bf16(af.v, bfrag, accB, 0, 0, 0);
            else
                accA = __builtin_amdgcn_mfma_f32_32x32x16_bf16(af.v, bfrag, accA, 0, 0, 0);
        }
    }

    // ---- land chunk1: its loads had 16 iters (~>=900cy) of cover ----
    #pragma unroll
    for (int q = 0; q < 4; ++q) {
        const int row = q * 8 + srow8;
        const int kf0 = 32 + 4 * sf4;             // chunk1 kf base for lane
        smem[wvS + (kf0 + 0) * 32 + row] = s1[q].x;
        smem[wvS + (kf0 + 1) * 32 + row] = s1[q].y;
        smem[wvS + (kf0 + 2) * 32 + row] = s1[q].z;
        smem[wvS + (kf0 + 3) * 32 + row] = s1[q].w;
    }

    // ================= chunk 1: t = 16..31 =================
    {
        float xc[4];
        #pragma unroll
        for (int j = 0; j < 4; ++j) xc[j] = sf[base0 + (16 + j) * 64];
        #pragma unroll
        for (int j = 0; j < 16; ++j) {
            const int t = 16 + j;
            const bf16x8 bfrag = bfc[t & 7];
            const float  xv    = xc[j & 3];
            if (t + 8 < 32) bfc[t & 7] = wq[(t + 8) * 64];
            if (j + 4 < 16) xc[j & 3] = sf[base0 + (t + 4) * 64];

            const float x2 = xv + xv;
            const float T2 = fmaf(x2, xv, -1.f);
            const float T3 = fmaf(x2, T2, -xv);
            const float T4 = fmaf(x2, T3, -T2);
            const float T5 = fmaf(x2, T4, -T3);
            const float T6 = fmaf(x2, T5, -T4);
            const float T7 = fmaf(x2, T6, -T5);
            unsigned R0 = pkbf_tr(1.f, xv);
            unsigned R1 = pkbf_tr(T2, T3);
            unsigned R2 = pkbf_tr(T4, T5);
            unsigned R3 = pkbf_tr(T6, T7);
            auto r02 = __builtin_amdgcn_permlane32_swap(R0, R2, false, false);
            auto r13 = __builtin_amdgcn_permlane32_swap(R1, R3, false, false);
            union { unsigned u[4]; bf16x8 v; } af;
            af.u[0] = r02[0]; af.u[1] = r02[1];
            af.u[2] = r13[0]; af.u[3] = r13[1];
            if (t & 1)
                accB = __builtin_amdgcn_mfma_f32_32x32x16_bf16(af.v, bfrag, accB, 0, 0, 0);
            else
                accA = __builtin_amdgcn_mfma_f32_32x32x16_bf16(af.v, bfrag, accA, 0, 0, 0);
        }
    }
    const f32x16 acc = accA + accB;

    // ---- partials into own (dead) slice: [rloc][o] at wvS + rloc*32 + o ----
    #pragma unroll
    for (int r = 0; r < 16; ++r) {
        const int rloc = (r & 3) + 8 * (r >> 2) + 4 * g;   // C/D row (HW-verified)
        smem[wvS + rloc * 32 + r0] = acc[r];
    }
    __syncthreads();                              // the block's ONLY barrier

    // ---- cross-wave reduce + coalesced f32x4 store of out[32][32] ----
    {
        float* op = out + rowB * 32;
        const int f = tid * 4;                    // 1024 floats / 256 thr
        f32x4 v0 = *(const f32x4*)&smem[f];
        f32x4 v1 = *(const f32x4*)&smem[2048 + f];
        f32x4 v2 = *(const f32x4*)&smem[4096 + f];
        f32x4 v3 = *(const f32x4*)&smem[6144 + f];
        f32x4 s = (v0 + v1) + (v2 + v3);
        *(f32x4*)(op + f) = s;
    }
}

extern "C" void kernel_launch(void* const* d_in, const int* in_sizes, int n_in,
                              void* d_out, int out_size, void* d_ws, size_t ws_size,
                              hipStream_t stream) {
    const float* x = (const float*)d_in[0];   // [65536, 256] fp32
    const float* w = (const float*)d_in[1];   // [32, 256, 8] fp32
    float* out = (float*)d_out;               // [65536, 32] fp32
    short* wB = (short*)d_ws;                 // 128 KB bf16 packed weights

    prep_w_kernel<<<256, 256, 0, stream>>>(w, wB);
    cheb_mm_kernel<<<2048, 256, 0, stream>>>(x, wB, out);
}